// Round 4
// baseline (186.475 us; speedup 1.0000x reference)
//
#include <hip/hip_runtime.h>
#include <math.h>

// B=16, S=1024, E=320, H=8, DH=40 -> M = 16384 rows.
// All heavy layers bf16 MFMA. 7 launches total via block-range megakernels.

#define M_ROWS 16384

typedef float f32x4 __attribute__((ext_vector_type(4)));
typedef __bf16 bf16x8 __attribute__((ext_vector_type(8)));
typedef unsigned short ushort_t;

typedef const __attribute__((address_space(1))) void* gas_ptr;
typedef __attribute__((address_space(3))) void* las_ptr;

__device__ __forceinline__ unsigned int f2bf(float f) {
    union { float f; unsigned int u; } v; v.f = f;
    unsigned int u = v.u + 0x7FFFu + ((v.u >> 16) & 1u);   // RNE
    return u >> 16;
}
__device__ __forceinline__ float bf2f(unsigned short s) {
    union { unsigned int u; float f; } v; v.u = ((unsigned int)s) << 16;
    return v.f;
}

// ---------------------------------------------------------------------------
// GEMM core (verified round 2): BM=128, BK=64, 4 waves, mfma 16x16x32 bf16.
// BN=64 -> wave grid 2x2 (64x32/wave); BN=32 -> 4x1 (32x32/wave).
// LDS row-major [rows][64] bf16, unit-XOR swizzle by (row&7); global_load_lds
// dest linear, SOURCE column pre-swizzled (both-sides rule #21).
// ---------------------------------------------------------------------------
template<int BN>
__device__ __forceinline__ void gemm_core(
    int tx, int ty,
    const ushort_t* __restrict__ X1, const ushort_t* __restrict__ X2,
    int ksplit, int K, const ushort_t* __restrict__ W,
    char* smem, f32x4 (*acc)[2])
{
    constexpr int BM = 128, BK = 64;
    constexpr int WROWS = (BN == 64) ? 2 : 4;
    constexpr int WCOLS = 4 / WROWS;
    constexpr int WM = BM / WROWS;
    constexpr int WN = BN / WCOLS;   // 32
    constexpr int MF = WM / 16;
    constexpr int NF = WN / 16;      // 2

    ushort_t* As = (ushort_t*)smem;
    ushort_t* Bs = As + BM * BK;

    const int tid  = threadIdx.x;
    const int wave = tid >> 6;
    const int lane = tid & 63;
    const int m0 = ty * BM;
    const int n0 = tx * BN;
    const int wr = wave / WCOLS;
    const int wc = wave % WCOLS;
    const int sr = lane >> 3;
    const int su = lane & 7;

    for (int k0 = 0; k0 < K; k0 += BK) {
        #pragma unroll
        for (int i = 0; i < (BM * BK * 2) / 4096; ++i) {
            const int c = i * 4 + wave;
            const int r = c * 8 + sr;
            const int gk = k0 + (su ^ (r & 7)) * 8;
            const ushort_t* src;
            if (gk < ksplit) src = X1 + (size_t)(m0 + r) * ksplit + gk;
            else             src = X2 + (size_t)(m0 + r) * (K - ksplit) + (gk - ksplit);
            __builtin_amdgcn_global_load_lds((gas_ptr)src, (las_ptr)&As[c * 512], 16, 0, 0);
        }
        #pragma unroll
        for (int i = 0; i < (BN * BK * 2) / 4096; ++i) {
            const int c = i * 4 + wave;
            const int r = c * 8 + sr;
            const int gk = k0 + (su ^ (r & 7)) * 8;
            const ushort_t* src = W + (size_t)(n0 + r) * K + gk;
            __builtin_amdgcn_global_load_lds((gas_ptr)src, (las_ptr)&Bs[c * 512], 16, 0, 0);
        }
        __syncthreads();

        #pragma unroll
        for (int s = 0; s < 2; ++s) {
            bf16x8 a[MF], b[NF];
            #pragma unroll
            for (int mf = 0; mf < MF; ++mf) {
                const int r  = wr * WM + mf * 16 + (lane & 15);
                const int lu = (s * 4 + (lane >> 4)) ^ (r & 7);
                a[mf] = *reinterpret_cast<const bf16x8*>(&As[r * 64 + lu * 8]);
            }
            #pragma unroll
            for (int nf = 0; nf < NF; ++nf) {
                const int r  = wc * WN + nf * 16 + (lane & 15);
                const int lu = (s * 4 + (lane >> 4)) ^ (r & 7);
                b[nf] = *reinterpret_cast<const bf16x8*>(&Bs[r * 64 + lu * 8]);
            }
            #pragma unroll
            for (int mf = 0; mf < MF; ++mf)
                #pragma unroll
                for (int nf = 0; nf < NF; ++nf)
                    acc[mf][nf] = __builtin_amdgcn_mfma_f32_16x16x32_bf16(
                        a[mf], b[nf], acc[mf][nf], 0, 0, 0);
        }
        __syncthreads();
    }
}

template<int BN, bool RELU>
__device__ __forceinline__ void gemm_store(
    int tx, int ty, f32x4 (*acc)[2], const float* __restrict__ bias,
    float* __restrict__ outF, ushort_t* __restrict__ outB, int N)
{
    constexpr int WROWS = (BN == 64) ? 2 : 4;
    constexpr int WCOLS = 4 / WROWS;
    constexpr int WM = 128 / WROWS;
    constexpr int WN = BN / WCOLS;
    constexpr int MF = WM / 16;

    const int tid  = threadIdx.x;
    const int wave = tid >> 6;
    const int lane = tid & 63;
    const int wr = wave / WCOLS;
    const int wc = wave % WCOLS;

    #pragma unroll
    for (int nf = 0; nf < 2; ++nf) {
        const int gn = tx * BN + wc * WN + nf * 16 + (lane & 15);
        const float bv = bias[gn];
        #pragma unroll
        for (int mf = 0; mf < MF; ++mf) {
            #pragma unroll
            for (int i = 0; i < 4; ++i) {
                const int gm = ty * 128 + wr * WM + mf * 16 + (lane >> 4) * 4 + i;
                float v = acc[mf][nf][i] + bv;
                if (RELU) v = fmaxf(v, 0.f);
                if (outF) outF[(size_t)gm * N + gn] = v;
                if (outB) outB[(size_t)gm * N + gn] = (ushort_t)f2bf(v);
            }
        }
    }
}

template<int BN, bool RELU>
__device__ __forceinline__ void gemm_full(
    int bid, int ntx,
    const ushort_t* X1, const ushort_t* X2, int ksplit, int K,
    const ushort_t* W, const float* bias,
    float* outF, ushort_t* outB, int N, char* smem)
{
    const int tx = bid % ntx, ty = bid / ntx;
    constexpr int MF = (BN == 64) ? 4 : 2;
    f32x4 acc[MF][2];
    #pragma unroll
    for (int i = 0; i < MF; ++i) { acc[i][0] = (f32x4)0.f; acc[i][1] = (f32x4)0.f; }
    gemm_core<BN>(tx, ty, X1, X2, ksplit, K, W, smem, acc);
    gemm_store<BN, RELU>(tx, ty, acc, bias, outF, outB, N);
}

// --- attention over batch axis (per (s,h): 16x16 scores over DH=40) ---------
__device__ __forceinline__ void attn_dev(
    int ab, const ushort_t* __restrict__ qkv, ushort_t* __restrict__ ctx, char* smem)
{
    float* q_s = (float*)smem;            // [16][40]
    float* k_s = q_s + 16 * 40;
    float* v_s = k_s + 16 * 40;
    float* p_s = v_s + 16 * 40;           // [16][16]

    const int s   = ab >> 3;
    const int h   = ab & 7;
    const int tid = threadIdx.x;
    const int hb  = h * 40;

    for (int idx = tid; idx < 16 * 40; idx += 256) {
        int l = idx / 40, d = idx % 40;
        size_t row = (size_t)(l * 1024 + s) * 960;
        q_s[idx] = bf2f(qkv[row + hb + d]);
        k_s[idx] = bf2f(qkv[row + 320 + hb + d]);
        v_s[idx] = bf2f(qkv[row + 640 + hb + d]);
    }
    __syncthreads();

    {
        int l = tid >> 4, m = tid & 15;
        float acc = 0.f;
        #pragma unroll
        for (int d = 0; d < 40; ++d) acc += q_s[l * 40 + d] * k_s[m * 40 + d];
        p_s[l * 16 + m] = acc * 0.15811388300841897f;   // 1/sqrt(40)
    }
    __syncthreads();

    if (tid < 16) {
        const int l = tid;
        float mx = p_s[l * 16];
        #pragma unroll
        for (int m = 1; m < 16; ++m) mx = fmaxf(mx, p_s[l * 16 + m]);
        float e[16]; float sum = 0.f;
        #pragma unroll
        for (int m = 0; m < 16; ++m) { e[m] = expf(p_s[l * 16 + m] - mx); sum += e[m]; }
        float inv = 1.0f / sum;
        #pragma unroll
        for (int m = 0; m < 16; ++m) p_s[l * 16 + m] = e[m] * inv;
    }
    __syncthreads();

    for (int idx = tid; idx < 16 * 40; idx += 256) {
        int l = idx / 40, d = idx % 40;
        float acc = 0.f;
        #pragma unroll
        for (int m = 0; m < 16; ++m) acc += p_s[l * 16 + m] * v_s[m * 40 + d];
        ctx[(size_t)(l * 1024 + s) * 320 + hb + d] = (ushort_t)f2bf(acc);
    }
}

// --- one wave per row, tiny N (1 or 3), K=160 -------------------------------
__device__ __forceinline__ void rowdot_dev(
    int row, const ushort_t* __restrict__ X, int K,
    const float* __restrict__ W, const float* __restrict__ bias,
    float* __restrict__ out, int N)
{
    const int lane = threadIdx.x & 63;
    for (int n = 0; n < N; ++n) {
        float s = 0.f;
        for (int j = lane; j < K; j += 64)
            s += bf2f(X[(size_t)row * K + j]) * W[(size_t)n * K + j];
        #pragma unroll
        for (int off = 32; off; off >>= 1) s += __shfl_down(s, off);
        if (lane == 0) out[(size_t)row * N + n] = s + bias[n];
    }
}

// ================================ kernels ===================================

struct ConvDesc { const float* src; ushort_t* dst; };
struct ConvPack { ConvDesc d[6]; int start[7]; };

// L1: blocks [0,1280): G1 = x -> [fp1(relu) | q | k | v], 128x128 tile,
//     fp32 A (x) and fp32 B ([fpW1|Wq|Wk|Wv]) reg-staged with inline bf16
//     conversion + dest-swizzled ds_write_b128 (write-swz == read-swz).
//     Blocks [1280, 1280+600): convert the 6 weight matrices later launches
//     need in bf16 (fpW1, fpW2, Wo, mW1, pW1, pW2).
__global__ __launch_bounds__(256) void k_g1(
    const float* __restrict__ xf,
    const float* __restrict__ fpW1, const float* __restrict__ Wq,
    const float* __restrict__ Wk, const float* __restrict__ Wv,
    const float* __restrict__ fpb1, const float* __restrict__ bq,
    const float* __restrict__ bk, const float* __restrict__ bvv,
    ushort_t* __restrict__ t1b, ushort_t* __restrict__ qkvb,
    ConvPack cp)
{
    __shared__ __align__(16) char smem[32 * 1024];
    const int bid = blockIdx.x;
    const int tid = threadIdx.x;

    if (bid >= 1280) {   // weight-conversion path
        const int cb = bid - 1280;
        int i = 0;
        #pragma unroll
        for (int t = 0; t < 6; ++t) if (cb >= cp.start[t + 1]) i = t + 1;
        const int idx = ((cb - cp.start[i]) * 256 + tid) * 4;
        float4 v = *reinterpret_cast<const float4*>(&cp.d[i].src[idx]);
        unsigned int lo = f2bf(v.x) | (f2bf(v.y) << 16);
        unsigned int hi = f2bf(v.z) | (f2bf(v.w) << 16);
        *reinterpret_cast<uint2*>(&cp.d[i].dst[idx]) = make_uint2(lo, hi);
        return;
    }

    constexpr int BM = 128, BK = 64;
    ushort_t* As = (ushort_t*)smem;
    ushort_t* Bs = As + BM * BK;

    const int tx = bid % 10, ty = bid / 10;
    const int wave = tid >> 6, lane = tid & 63;
    const int m0 = ty * BM, n0 = tx * 128;
    const int wr = wave >> 1, wc = wave & 1;

    f32x4 acc[4][4];
    #pragma unroll
    for (int i = 0; i < 4; ++i)
        #pragma unroll
        for (int j = 0; j < 4; ++j) acc[i][j] = (f32x4)0.f;

    for (int k0 = 0; k0 < 320; k0 += BK) {
        // A tile: 128 rows x 8 units (16B bf16), 4 chunks/thread
        #pragma unroll
        for (int i = 0; i < 4; ++i) {
            const int c = i * 256 + tid;
            const int r = c >> 3, u = c & 7;
            const float* src = xf + (size_t)(m0 + r) * 320 + k0 + u * 8;
            float4 f0 = *reinterpret_cast<const float4*>(src);
            float4 f1 = *reinterpret_cast<const float4*>(src + 4);
            uint4 pk;
            pk.x = f2bf(f0.x) | (f2bf(f0.y) << 16);
            pk.y = f2bf(f0.z) | (f2bf(f0.w) << 16);
            pk.z = f2bf(f1.x) | (f2bf(f1.y) << 16);
            pk.w = f2bf(f1.z) | (f2bf(f1.w) << 16);
            *reinterpret_cast<uint4*>(&As[r * 64 + (u ^ (r & 7)) * 8]) = pk;
        }
        // B tile: rows n0..n0+127 of concat [fpW1|Wq|Wk|Wv]
        #pragma unroll
        for (int i = 0; i < 4; ++i) {
            const int c = i * 256 + tid;
            const int r = c >> 3, u = c & 7;
            const int gn = n0 + r;
            const float* Wp; int off;
            if      (gn < 320) { Wp = fpW1; off = 0; }
            else if (gn < 640) { Wp = Wq;   off = 320; }
            else if (gn < 960) { Wp = Wk;   off = 640; }
            else               { Wp = Wv;   off = 960; }
            const float* src = Wp + (size_t)(gn - off) * 320 + k0 + u * 8;
            float4 f0 = *reinterpret_cast<const float4*>(src);
            float4 f1 = *reinterpret_cast<const float4*>(src + 4);
            uint4 pk;
            pk.x = f2bf(f0.x) | (f2bf(f0.y) << 16);
            pk.y = f2bf(f0.z) | (f2bf(f0.w) << 16);
            pk.z = f2bf(f1.x) | (f2bf(f1.y) << 16);
            pk.w = f2bf(f1.z) | (f2bf(f1.w) << 16);
            *reinterpret_cast<uint4*>(&Bs[r * 64 + (u ^ (r & 7)) * 8]) = pk;
        }
        __syncthreads();

        #pragma unroll
        for (int s = 0; s < 2; ++s) {
            bf16x8 a[4], b[4];
            #pragma unroll
            for (int mf = 0; mf < 4; ++mf) {
                const int r  = wr * 64 + mf * 16 + (lane & 15);
                const int lu = (s * 4 + (lane >> 4)) ^ (r & 7);
                a[mf] = *reinterpret_cast<const bf16x8*>(&As[r * 64 + lu * 8]);
            }
            #pragma unroll
            for (int nf = 0; nf < 4; ++nf) {
                const int r  = wc * 64 + nf * 16 + (lane & 15);
                const int lu = (s * 4 + (lane >> 4)) ^ (r & 7);
                b[nf] = *reinterpret_cast<const bf16x8*>(&Bs[r * 64 + lu * 8]);
            }
            #pragma unroll
            for (int mf = 0; mf < 4; ++mf)
                #pragma unroll
                for (int nf = 0; nf < 4; ++nf)
                    acc[mf][nf] = __builtin_amdgcn_mfma_f32_16x16x32_bf16(
                        a[mf], b[nf], acc[mf][nf], 0, 0, 0);
        }
        __syncthreads();
    }

    #pragma unroll
    for (int nf = 0; nf < 4; ++nf) {
        const int gn = n0 + wc * 64 + nf * 16 + (lane & 15);
        float bv;
        if      (gn < 320) bv = fpb1[gn];
        else if (gn < 640) bv = bq[gn - 320];
        else if (gn < 960) bv = bk[gn - 640];
        else               bv = bvv[gn - 960];
        #pragma unroll
        for (int mf = 0; mf < 4; ++mf) {
            #pragma unroll
            for (int i = 0; i < 4; ++i) {
                const int gm = m0 + wr * 64 + mf * 16 + (lane >> 4) * 4 + i;
                float v = acc[mf][nf][i] + bv;
                if (gn < 320) t1b [(size_t)gm * 320 + gn] = (ushort_t)f2bf(fmaxf(v, 0.f));
                else          qkvb[(size_t)gm * 960 + gn - 320] = (ushort_t)f2bf(v);
            }
        }
    }
}

// L2: blocks [0,640) G2 (t1b -> fp2 -> bb), [640,8832) attention (qkv -> ctx)
__global__ __launch_bounds__(256) void k_g2_attn(
    const ushort_t* __restrict__ t1b, const ushort_t* __restrict__ fpW2b,
    const float* __restrict__ fpb2, float* __restrict__ out_bb,
    ushort_t* __restrict__ bbB,
    const ushort_t* __restrict__ qkvb, ushort_t* __restrict__ ctxb)
{
    __shared__ __align__(16) char smem[24 * 1024];
    const int bid = blockIdx.x;
    if (bid < 640) gemm_full<64, false>(bid, 5, t1b, t1b, 320, 320, fpW2b, fpb2, out_bb, bbB, 320, smem);
    else           attn_dev(bid - 640, qkvb, ctxb, smem);
}

// L3: blocks [0,640) G3 (ctx -> Wo -> attn_out), [640,1280) G4 (bb -> fp1 relu)
__global__ __launch_bounds__(256) void k_g3_g4(
    const ushort_t* __restrict__ ctxb, const ushort_t* __restrict__ Wob,
    const float* __restrict__ bo, ushort_t* __restrict__ aoB,
    const ushort_t* __restrict__ bbB, const ushort_t* __restrict__ fpW1b,
    const float* __restrict__ fpb1, ushort_t* __restrict__ t2b)
{
    __shared__ __align__(16) char smem[24 * 1024];
    const int bid = blockIdx.x;
    if (bid < 640) gemm_full<64, false>(bid, 5, ctxb, ctxb, 320, 320, Wob, bo, nullptr, aoB, 320, smem);
    else           gemm_full<64, true >(bid - 640, 5, bbB, bbB, 320, 320, fpW1b, fpb1, nullptr, t2b, 320, smem);
}

// L4: blocks [0,640) G5 (t2 -> fp2 -> side), [640,1280) G6 (attn_out -> mW1 relu)
__global__ __launch_bounds__(256) void k_g5_g6(
    const ushort_t* __restrict__ t2b, const ushort_t* __restrict__ fpW2b,
    const float* __restrict__ fpb2, float* __restrict__ out_side,
    ushort_t* __restrict__ sideB,
    const ushort_t* __restrict__ aoB, const ushort_t* __restrict__ mW1b,
    const float* __restrict__ mb1, ushort_t* __restrict__ c1)
{
    __shared__ __align__(16) char smem[24 * 1024];
    const int bid = blockIdx.x;
    if (bid < 640) gemm_full<64, false>(bid, 5, t2b, t2b, 320, 320, fpW2b, fpb2, out_side, sideB, 320, smem);
    else           gemm_full<32, true >(bid - 640, 5, aoB, aoB, 320, 320, mW1b, mb1, nullptr, c1, 160, smem);
}

// L5: blocks [0,640) G7 ([bb|side] -> pW1 relu, K=640), [640,4736) rowdot -> prob
__global__ __launch_bounds__(256) void k_g7_rd(
    const ushort_t* __restrict__ bbB, const ushort_t* __restrict__ sideB,
    const ushort_t* __restrict__ pW1b, const float* __restrict__ pb1,
    ushort_t* __restrict__ t3,
    const ushort_t* __restrict__ c1, const float* __restrict__ mW2,
    const float* __restrict__ mb2, float* __restrict__ probF)
{
    __shared__ __align__(16) char smem[24 * 1024];
    const int bid = blockIdx.x;
    if (bid < 640) gemm_full<64, true>(bid, 5, bbB, sideB, 320, 640, pW1b, pb1, nullptr, t3, 320, smem);
    else           rowdot_dev((bid - 640) * 4 + ((int)threadIdx.x >> 6), c1, 160, mW2, mb2, probF, 1);
}

// L6: blocks [0,640) G8 (t3 -> pW2 relu, N=160), [640,17024) contact broadcast
__global__ __launch_bounds__(256) void k_g8_ct(
    const ushort_t* __restrict__ t3, const ushort_t* __restrict__ pW2b,
    const float* __restrict__ pb2, ushort_t* __restrict__ c2,
    const float* __restrict__ probF, float* __restrict__ out_cm)
{
    __shared__ __align__(16) char smem[24 * 1024];
    const int bid = blockIdx.x;
    if (bid < 640) {
        gemm_full<32, true>(bid, 5, t3, t3, 320, 320, pW2b, pb2, nullptr, c2, 160, smem);
    } else {
        const int row = bid - 640;
        const float p = probF[row];
        reinterpret_cast<float4*>(out_cm + (size_t)row * 1024)[threadIdx.x] =
            make_float4(p, p, p, p);
    }
}

// L7: rowdot c2 -> refined [M,3]
__global__ __launch_bounds__(256) void k_rd3(
    const ushort_t* __restrict__ c2, const float* __restrict__ pW3,
    const float* __restrict__ pb3, float* __restrict__ out_ref)
{
    rowdot_dev(blockIdx.x * 4 + ((int)threadIdx.x >> 6), c2, 160, pW3, pb3, out_ref, 3);
}

extern "C" void kernel_launch(void* const* d_in, const int* in_sizes, int n_in,
                              void* d_out, int out_size, void* d_ws, size_t ws_size,
                              hipStream_t stream)
{
    const float* x    = (const float*)d_in[0];
    const float* fpW1 = (const float*)d_in[1];
    const float* fpb1 = (const float*)d_in[2];
    const float* fpW2 = (const float*)d_in[3];
    const float* fpb2 = (const float*)d_in[4];
    const float* Wq   = (const float*)d_in[5];
    const float* bq   = (const float*)d_in[6];
    const float* Wk   = (const float*)d_in[7];
    const float* bk   = (const float*)d_in[8];
    const float* Wv   = (const float*)d_in[9];
    const float* bv   = (const float*)d_in[10];
    const float* Wo   = (const float*)d_in[11];
    const float* bo   = (const float*)d_in[12];
    const float* mW1  = (const float*)d_in[13];
    const float* mb1  = (const float*)d_in[14];
    const float* mW2  = (const float*)d_in[15];
    const float* mb2  = (const float*)d_in[16];
    const float* pW1  = (const float*)d_in[17];
    const float* pb1  = (const float*)d_in[18];
    const float* pW2  = (const float*)d_in[19];
    const float* pb2  = (const float*)d_in[20];
    const float* pW3  = (const float*)d_in[21];
    const float* pb3  = (const float*)d_in[22];

    float* out      = (float*)d_out;
    float* out_bb   = out;
    float* out_side = out + 5242880;
    float* out_cm   = out + 2 * 5242880;
    float* out_ref  = out + 2 * 5242880 + 16777216;

    ushort_t* ws = (ushort_t*)d_ws;
    const size_t BUF = 5242880;
    ushort_t* ctxb  = ws;              // ctx after attn; later c2 [M,160]
    ushort_t* t1b   = ws + 1 * BUF;    // fp1(x) relu; later t3 (pW1 out)
    ushort_t* bbB   = ws + 2 * BUF;
    ushort_t* sideB = ws + 3 * BUF;
    ushort_t* qkvb  = ws + 4 * BUF;    // [M,960] spans 3 BUFs; later aoB|t2b|c1
    ushort_t* wb    = ws + 7 * BUF;    // bf16 weights (conv'd inside k_g1)
    ushort_t* fpW1b = wb;              // 102400
    ushort_t* fpW2b = wb + 102400;     // 102400
    ushort_t* Wob   = wb + 204800;     // 102400
    ushort_t* mW1b  = wb + 307200;     // 51200
    ushort_t* pW1b  = wb + 358400;     // 204800
    ushort_t* pW2b  = wb + 563200;     // 51200
    float* probF = (float*)(ws + 7 * BUF + 655360);   // 16384 fp32

    ushort_t* aoB  = qkvb;             // aliases (lifetimes disjoint)
    ushort_t* t2b  = qkvb + BUF;
    ushort_t* c1   = qkvb + 2 * BUF;
    ushort_t* t3   = t1b;
    ushort_t* c2   = ctxb;

    dim3 blk(256);

    // conversions for all 6 weight matrices later launches consume in bf16
    ConvPack cp;
    const float* srcs[6] = {fpW1, fpW2, Wo, mW1, pW1, pW2};
    ushort_t*    dsts[6] = {fpW1b, fpW2b, Wob, mW1b, pW1b, pW2b};
    const int    nblk[6] = {100, 100, 100, 50, 200, 50};
    int acc_blk = 0;
    for (int i = 0; i < 6; ++i) {
        cp.d[i].src = srcs[i]; cp.d[i].dst = dsts[i];
        cp.start[i] = acc_blk; acc_blk += nblk[i];
    }
    cp.start[6] = acc_blk;   // 600

    // L1: G1 (1280 blocks, 128x128 tile, fused fp32->bf16) + conversions (600)
    k_g1<<<dim3(1280 + acc_blk), blk, 0, stream>>>(
        x, fpW1, Wq, Wk, Wv, fpb1, bq, bk, bv, t1b, qkvb, cp);
    // L2: G2 (backbone) || attention
    k_g2_attn<<<dim3(8832), blk, 0, stream>>>(t1b, fpW2b, fpb2, out_bb, bbB, qkvb, ctxb);
    // L3: G3 (Wo proj) || G4 (fp1(bb))
    k_g3_g4<<<dim3(1280), blk, 0, stream>>>(ctxb, Wob, bo, aoB, bbB, fpW1b, fpb1, t2b);
    // L4: G5 (fp2 -> side) || G6 (mW1, N=160)
    k_g5_g6<<<dim3(1280), blk, 0, stream>>>(t2b, fpW2b, fpb2, out_side, sideB, aoB, mW1b, mb1, c1);
    // L5: G7 (pW1, K=640) || rowdot (mW2 -> prob)
    k_g7_rd<<<dim3(4736), blk, 0, stream>>>(bbB, sideB, pW1b, pb1, t3, c1, mW2, mb2, probF);
    // L6: G8 (pW2, N=160) || contact broadcast
    k_g8_ct<<<dim3(17024), blk, 0, stream>>>(t3, pW2b, pb2, c2, probF, out_cm);
    // L7: rowdot (pW3 -> refined)
    k_rd3<<<dim3(4096), blk, 0, stream>>>(c2, pW3, pb3, out_ref);
}

// Round 5
// 172.803 us; speedup vs baseline: 1.0791x; 1.0791x over previous
//
#include <hip/hip_runtime.h>
#include <math.h>

// B=16, S=1024, E=320, H=8, DH=40 -> M = 16384 rows.
// All heavy layers bf16 MFMA. 8 launches via block-range megakernels.

#define M_ROWS 16384

typedef float f32x4 __attribute__((ext_vector_type(4)));
typedef __bf16 bf16x8 __attribute__((ext_vector_type(8)));
typedef unsigned short ushort_t;

typedef const __attribute__((address_space(1))) void* gas_ptr;
typedef __attribute__((address_space(3))) void* las_ptr;

__device__ __forceinline__ unsigned int f2bf(float f) {
    union { float f; unsigned int u; } v; v.f = f;
    unsigned int u = v.u + 0x7FFFu + ((v.u >> 16) & 1u);   // RNE
    return u >> 16;
}
__device__ __forceinline__ float bf2f(unsigned short s) {
    union { unsigned int u; float f; } v; v.u = ((unsigned int)s) << 16;
    return v.f;
}

// ---------------------------------------------------------------------------
// GEMM core (verified round 2): BM=128, BK=64, 4 waves, mfma 16x16x32 bf16.
// BN=64 -> wave grid 2x2 (64x32/wave); BN=32 -> 4x1 (32x32/wave).
// LDS row-major [rows][64] bf16, unit-XOR swizzle by (row&7); global_load_lds
// dest linear, SOURCE column pre-swizzled (both-sides rule #21).
// ---------------------------------------------------------------------------
template<int BN>
__device__ __forceinline__ void gemm_core(
    int tx, int ty,
    const ushort_t* __restrict__ X1, const ushort_t* __restrict__ X2,
    int ksplit, int K, const ushort_t* __restrict__ W,
    char* smem, f32x4 (*acc)[2])
{
    constexpr int BM = 128, BK = 64;
    constexpr int WROWS = (BN == 64) ? 2 : 4;
    constexpr int WCOLS = 4 / WROWS;
    constexpr int WM = BM / WROWS;
    constexpr int WN = BN / WCOLS;   // 32
    constexpr int MF = WM / 16;
    constexpr int NF = WN / 16;      // 2

    ushort_t* As = (ushort_t*)smem;
    ushort_t* Bs = As + BM * BK;

    const int tid  = threadIdx.x;
    const int wave = tid >> 6;
    const int lane = tid & 63;
    const int m0 = ty * BM;
    const int n0 = tx * BN;
    const int wr = wave / WCOLS;
    const int wc = wave % WCOLS;
    const int sr = lane >> 3;
    const int su = lane & 7;

    for (int k0 = 0; k0 < K; k0 += BK) {
        #pragma unroll
        for (int i = 0; i < (BM * BK * 2) / 4096; ++i) {
            const int c = i * 4 + wave;
            const int r = c * 8 + sr;
            const int gk = k0 + (su ^ (r & 7)) * 8;
            const ushort_t* src;
            if (gk < ksplit) src = X1 + (size_t)(m0 + r) * ksplit + gk;
            else             src = X2 + (size_t)(m0 + r) * (K - ksplit) + (gk - ksplit);
            __builtin_amdgcn_global_load_lds((gas_ptr)src, (las_ptr)&As[c * 512], 16, 0, 0);
        }
        #pragma unroll
        for (int i = 0; i < (BN * BK * 2) / 4096; ++i) {
            const int c = i * 4 + wave;
            const int r = c * 8 + sr;
            const int gk = k0 + (su ^ (r & 7)) * 8;
            const ushort_t* src = W + (size_t)(n0 + r) * K + gk;
            __builtin_amdgcn_global_load_lds((gas_ptr)src, (las_ptr)&Bs[c * 512], 16, 0, 0);
        }
        __syncthreads();

        #pragma unroll
        for (int s = 0; s < 2; ++s) {
            bf16x8 a[MF], b[NF];
            #pragma unroll
            for (int mf = 0; mf < MF; ++mf) {
                const int r  = wr * WM + mf * 16 + (lane & 15);
                const int lu = (s * 4 + (lane >> 4)) ^ (r & 7);
                a[mf] = *reinterpret_cast<const bf16x8*>(&As[r * 64 + lu * 8]);
            }
            #pragma unroll
            for (int nf = 0; nf < NF; ++nf) {
                const int r  = wc * WN + nf * 16 + (lane & 15);
                const int lu = (s * 4 + (lane >> 4)) ^ (r & 7);
                b[nf] = *reinterpret_cast<const bf16x8*>(&Bs[r * 64 + lu * 8]);
            }
            #pragma unroll
            for (int mf = 0; mf < MF; ++mf)
                #pragma unroll
                for (int nf = 0; nf < NF; ++nf)
                    acc[mf][nf] = __builtin_amdgcn_mfma_f32_16x16x32_bf16(
                        a[mf], b[nf], acc[mf][nf], 0, 0, 0);
        }
        __syncthreads();
    }
}

template<int BN, bool RELU>
__device__ __forceinline__ void gemm_store(
    int tx, int ty, f32x4 (*acc)[2], const float* __restrict__ bias,
    float* __restrict__ outF, ushort_t* __restrict__ outB, int N)
{
    constexpr int WROWS = (BN == 64) ? 2 : 4;
    constexpr int WCOLS = 4 / WROWS;
    constexpr int WM = 128 / WROWS;
    constexpr int WN = BN / WCOLS;
    constexpr int MF = WM / 16;

    const int tid  = threadIdx.x;
    const int wave = tid >> 6;
    const int lane = tid & 63;
    const int wr = wave / WCOLS;
    const int wc = wave % WCOLS;

    #pragma unroll
    for (int nf = 0; nf < 2; ++nf) {
        const int gn = tx * BN + wc * WN + nf * 16 + (lane & 15);
        const float bv = bias[gn];
        #pragma unroll
        for (int mf = 0; mf < MF; ++mf) {
            #pragma unroll
            for (int i = 0; i < 4; ++i) {
                const int gm = ty * 128 + wr * WM + mf * 16 + (lane >> 4) * 4 + i;
                float v = acc[mf][nf][i] + bv;
                if (RELU) v = fmaxf(v, 0.f);
                if (outF) outF[(size_t)gm * N + gn] = v;
                if (outB) outB[(size_t)gm * N + gn] = (ushort_t)f2bf(v);
            }
        }
    }
}

template<int BN, bool RELU>
__device__ __forceinline__ void gemm_full(
    int bid, int ntx,
    const ushort_t* X1, const ushort_t* X2, int ksplit, int K,
    const ushort_t* W, const float* bias,
    float* outF, ushort_t* outB, int N, char* smem)
{
    const int tx = bid % ntx, ty = bid / ntx;
    constexpr int MF = (BN == 64) ? 4 : 2;
    f32x4 acc[MF][2];
    #pragma unroll
    for (int i = 0; i < MF; ++i) { acc[i][0] = (f32x4)0.f; acc[i][1] = (f32x4)0.f; }
    gemm_core<BN>(tx, ty, X1, X2, ksplit, K, W, smem, acc);
    gemm_store<BN, RELU>(tx, ty, acc, bias, outF, outB, N);
}

// --- attention over batch axis (per (s,h): 16x16 scores over DH=40) ---------
// Softmax is wave-parallel: width-16 __shfl_xor reductions, all 256 lanes live.
__device__ __forceinline__ void attn_dev(
    int ab, const ushort_t* __restrict__ qkv, ushort_t* __restrict__ ctx, char* smem)
{
    float* q_s = (float*)smem;            // [16][40]
    float* k_s = q_s + 16 * 40;
    float* v_s = k_s + 16 * 40;
    float* p_s = v_s + 16 * 40;           // [16][16]

    const int s   = ab >> 3;
    const int h   = ab & 7;
    const int tid = threadIdx.x;
    const int hb  = h * 40;

    for (int idx = tid; idx < 16 * 40; idx += 256) {
        int l = idx / 40, d = idx % 40;
        size_t row = (size_t)(l * 1024 + s) * 960;
        q_s[idx] = bf2f(qkv[row + hb + d]);
        k_s[idx] = bf2f(qkv[row + 320 + hb + d]);
        v_s[idx] = bf2f(qkv[row + 640 + hb + d]);
    }
    __syncthreads();

    {
        const int l = tid >> 4, m = tid & 15;
        float sc = 0.f;
        #pragma unroll
        for (int d = 0; d < 40; ++d) sc += q_s[l * 40 + d] * k_s[m * 40 + d];
        sc *= 0.15811388300841897f;   // 1/sqrt(40)
        // row max / sum across the 16 lanes holding row l (contiguous lanes)
        float mx = sc;
        #pragma unroll
        for (int off = 1; off < 16; off <<= 1) mx = fmaxf(mx, __shfl_xor(mx, off, 16));
        float e = expf(sc - mx);
        float sum = e;
        #pragma unroll
        for (int off = 1; off < 16; off <<= 1) sum += __shfl_xor(sum, off, 16);
        p_s[l * 16 + m] = e / sum;
    }
    __syncthreads();

    for (int idx = tid; idx < 16 * 40; idx += 256) {
        int l = idx / 40, d = idx % 40;
        float acc = 0.f;
        #pragma unroll
        for (int m = 0; m < 16; ++m) acc += p_s[l * 16 + m] * v_s[m * 40 + d];
        ctx[(size_t)(l * 1024 + s) * 320 + hb + d] = (ushort_t)f2bf(acc);
    }
}

// --- one wave per row, tiny N (1 or 3), K=160 -------------------------------
__device__ __forceinline__ void rowdot_dev(
    int row, const ushort_t* __restrict__ X, int K,
    const float* __restrict__ W, const float* __restrict__ bias,
    float* __restrict__ out, int N)
{
    const int lane = threadIdx.x & 63;
    for (int n = 0; n < N; ++n) {
        float s = 0.f;
        for (int j = lane; j < K; j += 64)
            s += bf2f(X[(size_t)row * K + j]) * W[(size_t)n * K + j];
        #pragma unroll
        for (int off = 32; off; off >>= 1) s += __shfl_down(s, off);
        if (lane == 0) out[(size_t)row * N + n] = s + bias[n];
    }
}

// ================================ kernels ===================================

struct ConvDesc { const float* src; ushort_t* dst; };
struct ConvPack { ConvDesc d[10]; int start[11]; };

__global__ __launch_bounds__(256) void conv_all(ConvPack p)
{
    const int bid = blockIdx.x;
    int i = 0;
    #pragma unroll
    for (int t = 0; t < 10; ++t) if (bid >= p.start[t + 1]) i = t + 1;
    const int local = bid - p.start[i];
    const int idx = (local * 256 + (int)threadIdx.x) * 4;
    float4 v = *reinterpret_cast<const float4*>(&p.d[i].src[idx]);
    unsigned int lo = f2bf(v.x) | (f2bf(v.y) << 16);
    unsigned int hi = f2bf(v.z) | (f2bf(v.w) << 16);
    *reinterpret_cast<uint2*>(&p.d[i].dst[idx]) = make_uint2(lo, hi);
}

// G1: x -> [fp1(relu) | q | k | v], 128x128 tile, bf16 global_load_lds.
// XCD-aware mapping: all 10 tx column-tiles of one ty row-panel land on one
// XCD (bid%8), so xb is fetched from HBM once (1.3 MB/XCD, L2-resident).
__global__ __launch_bounds__(256) void k_g1(
    const ushort_t* __restrict__ xb, const ushort_t* __restrict__ Wcat,
    const float* __restrict__ fpb1, const float* __restrict__ bq,
    const float* __restrict__ bk, const float* __restrict__ bvv,
    ushort_t* __restrict__ t1b, ushort_t* __restrict__ qkvb)
{
    constexpr int BM = 128, BK = 64;
    __shared__ __align__(16) ushort_t As[BM * BK];
    __shared__ __align__(16) ushort_t Bs[BM * BK];

    const int bid = blockIdx.x;
    const int xcd = bid & 7;
    const int i0  = bid >> 3;             // 0..159
    const int ty  = xcd * 16 + (i0 & 15); // 0..127
    const int tx  = i0 >> 4;              // 0..9

    const int tid  = threadIdx.x;
    const int wave = tid >> 6;
    const int lane = tid & 63;
    const int m0 = ty * BM, n0 = tx * 128;
    const int wr = wave >> 1, wc = wave & 1;
    const int sr = lane >> 3, su = lane & 7;

    f32x4 acc[4][4];
    #pragma unroll
    for (int i = 0; i < 4; ++i)
        #pragma unroll
        for (int j = 0; j < 4; ++j) acc[i][j] = (f32x4)0.f;

    for (int k0 = 0; k0 < 320; k0 += BK) {
        #pragma unroll
        for (int i = 0; i < 4; ++i) {
            const int c = i * 4 + wave;
            const int r = c * 8 + sr;
            const int gk = k0 + (su ^ (r & 7)) * 8;
            __builtin_amdgcn_global_load_lds(
                (gas_ptr)(xb + (size_t)(m0 + r) * 320 + gk),
                (las_ptr)&As[c * 512], 16, 0, 0);
        }
        #pragma unroll
        for (int i = 0; i < 4; ++i) {
            const int c = i * 4 + wave;
            const int r = c * 8 + sr;
            const int gk = k0 + (su ^ (r & 7)) * 8;
            __builtin_amdgcn_global_load_lds(
                (gas_ptr)(Wcat + (size_t)(n0 + r) * 320 + gk),
                (las_ptr)&Bs[c * 512], 16, 0, 0);
        }
        __syncthreads();

        #pragma unroll
        for (int s = 0; s < 2; ++s) {
            bf16x8 a[4], b[4];
            #pragma unroll
            for (int mf = 0; mf < 4; ++mf) {
                const int r  = wr * 64 + mf * 16 + (lane & 15);
                const int lu = (s * 4 + (lane >> 4)) ^ (r & 7);
                a[mf] = *reinterpret_cast<const bf16x8*>(&As[r * 64 + lu * 8]);
            }
            #pragma unroll
            for (int nf = 0; nf < 4; ++nf) {
                const int r  = wc * 64 + nf * 16 + (lane & 15);
                const int lu = (s * 4 + (lane >> 4)) ^ (r & 7);
                b[nf] = *reinterpret_cast<const bf16x8*>(&Bs[r * 64 + lu * 8]);
            }
            #pragma unroll
            for (int mf = 0; mf < 4; ++mf)
                #pragma unroll
                for (int nf = 0; nf < 4; ++nf)
                    acc[mf][nf] = __builtin_amdgcn_mfma_f32_16x16x32_bf16(
                        a[mf], b[nf], acc[mf][nf], 0, 0, 0);
        }
        __syncthreads();
    }

    #pragma unroll
    for (int nf = 0; nf < 4; ++nf) {
        const int gn = n0 + wc * 64 + nf * 16 + (lane & 15);
        float bv;
        if      (gn < 320) bv = fpb1[gn];
        else if (gn < 640) bv = bq[gn - 320];
        else if (gn < 960) bv = bk[gn - 640];
        else               bv = bvv[gn - 960];
        #pragma unroll
        for (int mf = 0; mf < 4; ++mf) {
            #pragma unroll
            for (int i = 0; i < 4; ++i) {
                const int gm = m0 + wr * 64 + mf * 16 + (lane >> 4) * 4 + i;
                float v = acc[mf][nf][i] + bv;
                if (gn < 320) t1b [(size_t)gm * 320 + gn] = (ushort_t)f2bf(fmaxf(v, 0.f));
                else          qkvb[(size_t)gm * 960 + gn - 320] = (ushort_t)f2bf(v);
            }
        }
    }
}

// L3: blocks [0,640) G2 (t1b -> fp2 -> bb), [640,8832) attention (qkv -> ctx)
__global__ __launch_bounds__(256) void k_g2_attn(
    const ushort_t* __restrict__ t1b, const ushort_t* __restrict__ fpW2b,
    const float* __restrict__ fpb2, float* __restrict__ out_bb,
    ushort_t* __restrict__ bbB,
    const ushort_t* __restrict__ qkvb, ushort_t* __restrict__ ctxb)
{
    __shared__ __align__(16) char smem[24 * 1024];
    const int bid = blockIdx.x;
    if (bid < 640) gemm_full<64, false>(bid, 5, t1b, t1b, 320, 320, fpW2b, fpb2, out_bb, bbB, 320, smem);
    else           attn_dev(bid - 640, qkvb, ctxb, smem);
}

// L4: blocks [0,640) G3 (ctx -> Wo -> attn_out), [640,1280) G4 (bb -> fp1 relu)
__global__ __launch_bounds__(256) void k_g3_g4(
    const ushort_t* __restrict__ ctxb, const ushort_t* __restrict__ Wob,
    const float* __restrict__ bo, ushort_t* __restrict__ aoB,
    const ushort_t* __restrict__ bbB, const ushort_t* __restrict__ fpW1b,
    const float* __restrict__ fpb1, ushort_t* __restrict__ t2b)
{
    __shared__ __align__(16) char smem[24 * 1024];
    const int bid = blockIdx.x;
    if (bid < 640) gemm_full<64, false>(bid, 5, ctxb, ctxb, 320, 320, Wob, bo, nullptr, aoB, 320, smem);
    else           gemm_full<64, true >(bid - 640, 5, bbB, bbB, 320, 320, fpW1b, fpb1, nullptr, t2b, 320, smem);
}

// L5: blocks [0,640) G5 (t2 -> fp2 -> side), [640,1280) G6 (attn_out -> mW1 relu)
__global__ __launch_bounds__(256) void k_g5_g6(
    const ushort_t* __restrict__ t2b, const ushort_t* __restrict__ fpW2b,
    const float* __restrict__ fpb2, float* __restrict__ out_side,
    ushort_t* __restrict__ sideB,
    const ushort_t* __restrict__ aoB, const ushort_t* __restrict__ mW1b,
    const float* __restrict__ mb1, ushort_t* __restrict__ c1)
{
    __shared__ __align__(16) char smem[24 * 1024];
    const int bid = blockIdx.x;
    if (bid < 640) gemm_full<64, false>(bid, 5, t2b, t2b, 320, 320, fpW2b, fpb2, out_side, sideB, 320, smem);
    else           gemm_full<32, true >(bid - 640, 5, aoB, aoB, 320, 320, mW1b, mb1, nullptr, c1, 160, smem);
}

// L6: blocks [0,640) G7 ([bb|side] -> pW1 relu, K=640), [640,4736) rowdot -> prob
__global__ __launch_bounds__(256) void k_g7_rd(
    const ushort_t* __restrict__ bbB, const ushort_t* __restrict__ sideB,
    const ushort_t* __restrict__ pW1b, const float* __restrict__ pb1,
    ushort_t* __restrict__ t3,
    const ushort_t* __restrict__ c1, const float* __restrict__ mW2,
    const float* __restrict__ mb2, float* __restrict__ probF)
{
    __shared__ __align__(16) char smem[24 * 1024];
    const int bid = blockIdx.x;
    if (bid < 640) gemm_full<64, true>(bid, 5, bbB, sideB, 320, 640, pW1b, pb1, nullptr, t3, 320, smem);
    else           rowdot_dev((bid - 640) * 4 + ((int)threadIdx.x >> 6), c1, 160, mW2, mb2, probF, 1);
}

// L7: blocks [0,640) G8 (t3 -> pW2 relu, N=160), [640,17024) contact broadcast
__global__ __launch_bounds__(256) void k_g8_ct(
    const ushort_t* __restrict__ t3, const ushort_t* __restrict__ pW2b,
    const float* __restrict__ pb2, ushort_t* __restrict__ c2,
    const float* __restrict__ probF, float* __restrict__ out_cm)
{
    __shared__ __align__(16) char smem[24 * 1024];
    const int bid = blockIdx.x;
    if (bid < 640) {
        gemm_full<32, true>(bid, 5, t3, t3, 320, 320, pW2b, pb2, nullptr, c2, 160, smem);
    } else {
        const int row = bid - 640;
        const float p = probF[row];
        reinterpret_cast<float4*>(out_cm + (size_t)row * 1024)[threadIdx.x] =
            make_float4(p, p, p, p);
    }
}

// L8: rowdot c2 -> refined [M,3]
__global__ __launch_bounds__(256) void k_rd3(
    const ushort_t* __restrict__ c2, const float* __restrict__ pW3,
    const float* __restrict__ pb3, float* __restrict__ out_ref)
{
    rowdot_dev(blockIdx.x * 4 + ((int)threadIdx.x >> 6), c2, 160, pW3, pb3, out_ref, 3);
}

extern "C" void kernel_launch(void* const* d_in, const int* in_sizes, int n_in,
                              void* d_out, int out_size, void* d_ws, size_t ws_size,
                              hipStream_t stream)
{
    const float* x    = (const float*)d_in[0];
    const float* fpW1 = (const float*)d_in[1];
    const float* fpb1 = (const float*)d_in[2];
    const float* fpW2 = (const float*)d_in[3];
    const float* fpb2 = (const float*)d_in[4];
    const float* Wq   = (const float*)d_in[5];
    const float* bq   = (const float*)d_in[6];
    const float* Wk   = (const float*)d_in[7];
    const float* bk   = (const float*)d_in[8];
    const float* Wv   = (const float*)d_in[9];
    const float* bv   = (const float*)d_in[10];
    const float* Wo   = (const float*)d_in[11];
    const float* bo   = (const float*)d_in[12];
    const float* mW1  = (const float*)d_in[13];
    const float* mb1  = (const float*)d_in[14];
    const float* mW2  = (const float*)d_in[15];
    const float* mb2  = (const float*)d_in[16];
    const float* pW1  = (const float*)d_in[17];
    const float* pb1  = (const float*)d_in[18];
    const float* pW2  = (const float*)d_in[19];
    const float* pb2  = (const float*)d_in[20];
    const float* pW3  = (const float*)d_in[21];
    const float* pb3  = (const float*)d_in[22];

    float* out      = (float*)d_out;
    float* out_bb   = out;
    float* out_side = out + 5242880;
    float* out_cm   = out + 2 * 5242880;
    float* out_ref  = out + 2 * 5242880 + 16777216;

    ushort_t* ws = (ushort_t*)d_ws;
    const size_t BUF = 5242880;
    ushort_t* xb    = ws;              // x bf16; later ctx; later c2 [M,160]
    ushort_t* t1b   = ws + 1 * BUF;    // fp1(x) relu; later t3 (pW1 out)
    ushort_t* bbB   = ws + 2 * BUF;
    ushort_t* sideB = ws + 3 * BUF;
    ushort_t* qkvb  = ws + 4 * BUF;    // [M,960] spans 3 BUFs; later aoB|t2b|c1
    ushort_t* wb    = ws + 7 * BUF;
    ushort_t* fpW1b = wb;              // Wcat = [fpW1|Wq|Wk|Wv] contiguous
    ushort_t* Wqb   = wb + 102400;
    ushort_t* Wkb   = wb + 204800;
    ushort_t* Wvb   = wb + 307200;
    ushort_t* fpW2b = wb + 409600;
    ushort_t* Wob   = wb + 512000;
    ushort_t* mW1b  = wb + 614400;
    ushort_t* pW1b  = wb + 665600;
    ushort_t* pW2b  = wb + 870400;
    float* probF = (float*)(ws + 7 * BUF + 921600);

    ushort_t* ctxb = xb;               // aliases (lifetimes disjoint)
    ushort_t* aoB  = qkvb;
    ushort_t* t2b  = qkvb + BUF;
    ushort_t* c1   = qkvb + 2 * BUF;
    ushort_t* t3   = t1b;
    ushort_t* c2   = xb;

    dim3 blk(256);

    // L1: all fp32->bf16 conversions (x + 9 weight matrices)
    ConvPack cp;
    const float* srcs[10] = {x, fpW1, Wq, Wk, Wv, fpW2, Wo, mW1, pW1, pW2};
    ushort_t*    dsts[10] = {xb, fpW1b, Wqb, Wkb, Wvb, fpW2b, Wob, mW1b, pW1b, pW2b};
    const int    nblk[10] = {5120, 100, 100, 100, 100, 100, 100, 50, 200, 50};
    int acc_blk = 0;
    for (int i = 0; i < 10; ++i) {
        cp.d[i].src = srcs[i]; cp.d[i].dst = dsts[i];
        cp.start[i] = acc_blk; acc_blk += nblk[i];
    }
    cp.start[10] = acc_blk;
    conv_all<<<dim3(acc_blk), blk, 0, stream>>>(cp);

    // L2: x -> [fp1 relu | q | k | v] (128x128 tile, XCD-aware)
    k_g1<<<dim3(1280), blk, 0, stream>>>(xb, wb, fpb1, bq, bk, bv, t1b, qkvb);
    // L3: G2 (backbone) || attention
    k_g2_attn<<<dim3(8832), blk, 0, stream>>>(t1b, fpW2b, fpb2, out_bb, bbB, qkvb, ctxb);
    // L4: G3 (Wo proj) || G4 (fp1(bb))
    k_g3_g4<<<dim3(1280), blk, 0, stream>>>(ctxb, Wob, bo, aoB, bbB, fpW1b, fpb1, t2b);
    // L5: G5 (fp2 -> side) || G6 (mW1, N=160)
    k_g5_g6<<<dim3(1280), blk, 0, stream>>>(t2b, fpW2b, fpb2, out_side, sideB, aoB, mW1b, mb1, c1);
    // L6: G7 (pW1, K=640) || rowdot (mW2 -> prob)
    k_g7_rd<<<dim3(4736), blk, 0, stream>>>(bbB, sideB, pW1b, pb1, t3, c1, mW2, mb2, probF);
    // L7: G8 (pW2, N=160) || contact broadcast
    k_g8_ct<<<dim3(17024), blk, 0, stream>>>(t3, pW2b, pb2, c2, probF, out_cm);
    // L8: rowdot (pW3 -> refined)
    k_rd3<<<dim3(4096), blk, 0, stream>>>(c2, pW3, pb3, out_ref);
}